// Round 1
// baseline (705.287 us; speedup 1.0000x reference)
//
#include <hip/hip_runtime.h>
#include <math.h>

#define N_VAR 8192
#define N_CHK 4096
#define DV 3
#define N_EDGE (N_VAR * DV)
#define BATCH 128
#define T_ITERS 30
#define ELLW 24
#define CHNK 8

#define LOG2E 1.44269504088896340736f
#define LN2   0.69314718055994530942f

// tanh(x/2), sign preserved, |t| floored at 1e-7 (matches reference clamp);
// x pre-clipped to [-15,15]
__device__ __forceinline__ float tanh_half(float x) {
    float ex = __builtin_amdgcn_exp2f(x * LOG2E);              // e^x
    float t = 1.0f - 2.0f * __builtin_amdgcn_rcpf(ex + 1.0f);
    float s = (x < 0.0f) ? -1.0f : 1.0f;
    return s * fmaxf(fabsf(t), 1e-7f);
}

// 2*atanh(clip(p)) — reference's clip(-1+eps, 1-eps) then 2 atanh
__device__ __forceinline__ float atanh2(float p) {
    const float lim = 1.0f - 1e-7f;
    p = fminf(fmaxf(p, -lim), lim);
    return (__builtin_amdgcn_logf(1.0f + p) -
            __builtin_amdgcn_logf(1.0f - p)) * LN2;
}

// ---------------- graph build (once per launch) ----------------------------

__global__ void k_ell_scatter(const int* __restrict__ edge_chk,
                              int* __restrict__ deg_arr, int* __restrict__ ell_e) {
    int e = blockIdx.x * blockDim.x + threadIdx.x;
    if (e < N_EDGE) {
        int c = edge_chk[e];
        int pos = atomicAdd(&deg_arr[c], 1);
        if (pos < ELLW) ell_e[c * ELLW + pos] = e;   // store EDGE id
    }
}

// exclusive prefix over 4096 degs -> ptr (compact slot offsets)
__global__ __launch_bounds__(1024) void k_scan(const int* __restrict__ counts,
                                               int* __restrict__ ptr) {
    __shared__ int bufA[1024];
    __shared__ int bufB[1024];
    int t = threadIdx.x;
    int c0 = counts[4 * t + 0];
    int c1 = counts[4 * t + 1];
    int c2 = counts[4 * t + 2];
    int c3 = counts[4 * t + 3];
    int s = c0 + c1 + c2 + c3;
    bufA[t] = s;
    __syncthreads();
    int* src = bufA;
    int* dst = bufB;
    for (int off = 1; off < 1024; off *= 2) {
        int v = src[t];
        if (t >= off) v += src[t - off];
        dst[t] = v;
        __syncthreads();
        int* tmp = src; src = dst; dst = tmp;
    }
    int incl = src[t];
    int excl = incl - s;
    ptr[4 * t + 0] = excl;
    ptr[4 * t + 1] = excl + c0;
    ptr[4 * t + 2] = excl + c0 + c1;
    ptr[4 * t + 3] = excl + c0 + c1 + c2;
    if (t == 1023) ptr[N_CHK] = incl;
}

// slot_e[e] = compact slot of edge e
__global__ void k_slotmap(const int* __restrict__ ell_e,
                          const int* __restrict__ deg_arr,
                          const int* __restrict__ ptr,
                          int* __restrict__ slot_e) {
    int gid = blockIdx.x * 256 + threadIdx.x;
    if (gid < N_CHK * ELLW) {
        int c = gid / ELLW;
        int j = gid - c * ELLW;
        int d = deg_arr[c]; if (d > ELLW) d = ELLW;
        if (j < d) slot_e[ell_e[gid]] = ptr[c] + j;
    }
}

// recs[slot] = {slot of var's edge0, edge1, edge2, edge id}
__global__ void k_pack(const int* __restrict__ slot_e, int4* __restrict__ recs) {
    int e = blockIdx.x * 256 + threadIdx.x;
    if (e < N_EDGE) {
        int v = e / 3;
        int4 r;
        r.x = slot_e[3 * v + 0];
        r.y = slot_e[3 * v + 1];
        r.z = slot_e[3 * v + 2];
        r.w = e;
        recs[slot_e[e]] = r;
    }
}

// ---------------- one BP iteration: block (128 thr) per check --------------
// c2v ping-pong (f32): read prev, write curr -> no intra-launch races.
// posterior of iteration t-1 computed on the fly from c2v_prev; the owner
// edge (e%3==0) writes it to out[t-1] with a plain NT store (no atomics).

__global__ __launch_bounds__(128) void k_iter(
        const float* __restrict__ chn,
        const float* __restrict__ c2v_prev,
        float* __restrict__ c2v_curr,
        _Float16* __restrict__ v2c,
        float* __restrict__ out_prev,
        const int have_out,
        const float* __restrict__ gamma_logit,
        const int4* __restrict__ recs,
        const int* __restrict__ deg_arr,
        const int* __restrict__ ptr) {
    int c = blockIdx.x;
    int b = threadIdx.x;
    int deg = deg_arr[c];
    if (deg > ELLW) deg = ELLW;
    if (deg == 0) return;
    int base = ptr[c];
    float g = 1.0f / (1.0f + __builtin_amdgcn_exp2f(-gamma_logit[0] * LOG2E));
    float om = 1.0f - g;

    float tv[ELLW];

    // Process edges in batches of CHNK: loads unconditional (clamped) within a
    // batch so the compiler can pipeline them; one uniform branch per batch.
#define BATCH_BODY(J0)                                                         \
    {                                                                          \
        int4 r[CHNK]; float m0[CHNK], m1[CHNK], m2[CHNK], cv[CHNK], vo[CHNK];  \
        _Pragma("unroll")                                                      \
        for (int u = 0; u < CHNK; ++u) {                                       \
            int s = base + (J0) + u;                                           \
            s = (s < N_EDGE) ? s : (N_EDGE - 1);                               \
            r[u] = recs[s];                                                    \
        }                                                                      \
        _Pragma("unroll")                                                      \
        for (int u = 0; u < CHNK; ++u) {                                       \
            int s = base + (J0) + u;                                           \
            s = (s < N_EDGE) ? s : (N_EDGE - 1);                               \
            m0[u] = c2v_prev[r[u].x * BATCH + b];                              \
            m1[u] = c2v_prev[r[u].y * BATCH + b];                              \
            m2[u] = c2v_prev[r[u].z * BATCH + b];                              \
            cv[u] = chn[(r[u].w / 3) * BATCH + b];                             \
            vo[u] = (float)v2c[s * BATCH + b];                                 \
        }                                                                      \
        _Pragma("unroll")                                                      \
        for (int u = 0; u < CHNK; ++u) {                                       \
            int j = (J0) + u;                                                  \
            if (j < deg) {                                                     \
                int self = base + j;                                           \
                int v = r[u].w / 3;                                            \
                float post = cv[u] + m0[u] + m1[u] + m2[u];                    \
                float cp = (r[u].x == self) ? m0[u]                            \
                           : ((r[u].y == self) ? m1[u] : m2[u]);               \
                float vn = g * (post - cp) + om * vo[u];                       \
                v2c[self * BATCH + b] = (_Float16)vn;                          \
                if (have_out && (r[u].w == 3 * v)) {                           \
                    __builtin_nontemporal_store(post,                          \
                        &out_prev[v * BATCH + b]);                             \
                }                                                              \
                float x = fminf(fmaxf(vn, -15.0f), 15.0f);                     \
                tv[j] = tanh_half(x);                                          \
            }                                                                  \
        }                                                                      \
    }

    BATCH_BODY(0)
    if (deg > CHNK) BATCH_BODY(CHNK)
    if (deg > 2 * CHNK) BATCH_BODY(2 * CHNK)
#undef BATCH_BODY

    // suffix products: ext[j] = prod_{k>j} tv[k]
    float ext[ELLW];
    float run = 1.0f;
#pragma unroll
    for (int j = ELLW - 1; j >= 0; --j) {
        if (j < deg) { ext[j] = run; run *= tv[j]; }
    }
    // prefix sweep + emit C2V (f32, compact, coalesced)
    float pfx = 1.0f;
#pragma unroll
    for (int j = 0; j < ELLW; ++j) {
        if (j < deg) {
            float p = pfx * ext[j];
            pfx *= tv[j];
            float m = atanh2(p);
            c2v_curr[(base + j) * BATCH + b] = m;
        }
    }
}

// ---------------- final posterior slice (var-centric, coalesced) -----------

__global__ __launch_bounds__(256) void k_final(
        const float* __restrict__ chn, const float* __restrict__ c2v,
        const int* __restrict__ slot_e, float* __restrict__ out_last) {
    int gid = blockIdx.x * 256 + threadIdx.x;   // 0 .. N_VAR*BATCH-1
    int v = gid >> 7;
    int b = gid & 127;
    int s0 = slot_e[3 * v + 0];
    int s1 = slot_e[3 * v + 1];
    int s2 = slot_e[3 * v + 2];
    float acc = chn[gid] + c2v[s0 * BATCH + b] + c2v[s1 * BATCH + b] +
                c2v[s2 * BATCH + b];
    __builtin_nontemporal_store(acc, &out_last[gid]);
}

// ---------------- Launch ---------------------------------------------------

extern "C" void kernel_launch(void* const* d_in, const int* in_sizes, int n_in,
                              void* d_out, int out_size, void* d_ws, size_t ws_size,
                              hipStream_t stream) {
    const float* chn         = (const float*)d_in[0];
    const float* gamma_logit = (const float*)d_in[1];
    // d_in[2] = edge_var (deterministic: e/3) — not needed
    const int* edge_chk      = (const int*)d_in[3];
    float* out = (float*)d_out;

    const size_t MSG = (size_t)N_EDGE * BATCH;
    float* c2vA      = (float*)d_ws;                       // f32 ping
    float* c2vB      = c2vA + MSG;                         // f32 pong
    _Float16* v2c    = (_Float16*)(c2vB + MSG);            // fp16
    int4* recs       = (int4*)(v2c + MSG);                 // per-slot records
    int* slot_e      = (int*)(recs + N_EDGE);
    int* ell_e       = slot_e + N_EDGE;
    int* deg_arr     = ell_e + (size_t)N_CHK * ELLW;
    int* ptr         = deg_arr + N_CHK;                    // N_CHK+1 ints

    (void)hipMemsetAsync(c2vA, 0, MSG * sizeof(float), stream);
    (void)hipMemsetAsync(v2c, 0, MSG * sizeof(_Float16), stream);
    (void)hipMemsetAsync(slot_e, 0, (size_t)N_EDGE * sizeof(int), stream);
    (void)hipMemsetAsync(deg_arr, 0, N_CHK * sizeof(int), stream);

    k_ell_scatter<<<(N_EDGE + 255) / 256, 256, 0, stream>>>(edge_chk, deg_arr,
                                                            ell_e);
    k_scan<<<1, 1024, 0, stream>>>(deg_arr, ptr);
    k_slotmap<<<(N_CHK * ELLW + 255) / 256, 256, 0, stream>>>(ell_e, deg_arr,
                                                              ptr, slot_e);
    k_pack<<<(N_EDGE + 255) / 256, 256, 0, stream>>>(slot_e, recs);

    const size_t SLICE = (size_t)N_VAR * BATCH;
    float* bufs[2] = {c2vA, c2vB};
    for (int t = 0; t < T_ITERS; ++t) {
        const float* prev = bufs[t & 1];
        float* curr = bufs[(t + 1) & 1];
        float* out_prev = (t == 0) ? out : out + (size_t)(t - 1) * SLICE;
        k_iter<<<N_CHK, 128, 0, stream>>>(chn, prev, curr, v2c, out_prev,
                                          (t > 0) ? 1 : 0, gamma_logit, recs,
                                          deg_arr, ptr);
    }
    // out[T-1] = chn + sum of final c2v (final buffer = bufs[T_ITERS & 1])
    k_final<<<(N_VAR * BATCH) / 256, 256, 0, stream>>>(
        chn, bufs[T_ITERS & 1], slot_e, out + (size_t)(T_ITERS - 1) * SLICE);
}

// Round 2
// 618.216 us; speedup vs baseline: 1.1408x; 1.1408x over previous
//
#include <hip/hip_runtime.h>
#include <math.h>

#define N_VAR 8192
#define N_CHK 4096
#define DV 3
#define N_EDGE (N_VAR * DV)
#define BATCH 128
#define T_ITERS 30
#define ELLW 24
#define CHNK 8

#define LOG2E 1.44269504088896340736f
#define LN2   0.69314718055994530942f

// tanh(x/2), sign preserved, |t| floored at 1e-7 (matches reference clamp);
// x pre-clipped to [-15,15]
__device__ __forceinline__ float tanh_half(float x) {
    float ex = __builtin_amdgcn_exp2f(x * LOG2E);              // e^x
    float t = 1.0f - 2.0f * __builtin_amdgcn_rcpf(ex + 1.0f);
    float s = (x < 0.0f) ? -1.0f : 1.0f;
    return s * fmaxf(fabsf(t), 1e-7f);
}

// 2*atanh(clip(p)) — reference's clip(-1+eps, 1-eps) then 2 atanh
__device__ __forceinline__ float atanh2(float p) {
    const float lim = 1.0f - 1e-7f;
    p = fminf(fmaxf(p, -lim), lim);
    return (__builtin_amdgcn_logf(1.0f + p) -
            __builtin_amdgcn_logf(1.0f - p)) * LN2;
}

// ---------------- graph build (once per launch) ----------------------------

__global__ void k_ell_scatter(const int* __restrict__ edge_chk,
                              int* __restrict__ deg_arr, int* __restrict__ ell_e) {
    int e = blockIdx.x * blockDim.x + threadIdx.x;
    if (e < N_EDGE) {
        int c = edge_chk[e];
        int pos = atomicAdd(&deg_arr[c], 1);
        if (pos < ELLW) ell_e[c * ELLW + pos] = e;   // store EDGE id
    }
}

// exclusive prefix over 4096 degs -> ptr (compact slot offsets)
__global__ __launch_bounds__(1024) void k_scan(const int* __restrict__ counts,
                                               int* __restrict__ ptr) {
    __shared__ int bufA[1024];
    __shared__ int bufB[1024];
    int t = threadIdx.x;
    int c0 = counts[4 * t + 0];
    int c1 = counts[4 * t + 1];
    int c2 = counts[4 * t + 2];
    int c3 = counts[4 * t + 3];
    int s = c0 + c1 + c2 + c3;
    bufA[t] = s;
    __syncthreads();
    int* src = bufA;
    int* dst = bufB;
    for (int off = 1; off < 1024; off *= 2) {
        int v = src[t];
        if (t >= off) v += src[t - off];
        dst[t] = v;
        __syncthreads();
        int* tmp = src; src = dst; dst = tmp;
    }
    int incl = src[t];
    int excl = incl - s;
    ptr[4 * t + 0] = excl;
    ptr[4 * t + 1] = excl + c0;
    ptr[4 * t + 2] = excl + c0 + c1;
    ptr[4 * t + 3] = excl + c0 + c1 + c2;
    if (t == 1023) ptr[N_CHK] = incl;
}

// slot_e[e] = compact slot of edge e
__global__ void k_slotmap(const int* __restrict__ ell_e,
                          const int* __restrict__ deg_arr,
                          const int* __restrict__ ptr,
                          int* __restrict__ slot_e) {
    int gid = blockIdx.x * 256 + threadIdx.x;
    if (gid < N_CHK * ELLW) {
        int c = gid / ELLW;
        int j = gid - c * ELLW;
        int d = deg_arr[c]; if (d > ELLW) d = ELLW;
        if (j < d) slot_e[ell_e[gid]] = ptr[c] + j;
    }
}

// recs[slot] = {slot of var's edge0, edge1, edge2, (v<<2)|lane_of_var}
__global__ void k_pack(const int* __restrict__ slot_e, int4* __restrict__ recs) {
    int e = blockIdx.x * 256 + threadIdx.x;
    if (e < N_EDGE) {
        int v = e / 3;
        int4 r;
        r.x = slot_e[3 * v + 0];
        r.y = slot_e[3 * v + 1];
        r.z = slot_e[3 * v + 2];
        r.w = (v << 2) | (e - 3 * v);
        recs[slot_e[e]] = r;
    }
}

// ---------------- one BP iteration: block (128 thr) per check --------------
// c2v ping-pong (fp16): read prev, write curr -> no intra-launch races.
// posterior of iteration t-1 computed on the fly from c2v_prev; the owner
// edge (e%3==0) writes it to out[t-1] with a plain NT store (no atomics).

__global__ __launch_bounds__(128) void k_iter(
        const float* __restrict__ chn,
        const _Float16* __restrict__ c2v_prev,
        _Float16* __restrict__ c2v_curr,
        _Float16* __restrict__ v2c,
        float* __restrict__ out_prev,
        const int have_out,
        const float* __restrict__ gamma_logit,
        const int4* __restrict__ recs,
        const int* __restrict__ deg_arr,
        const int* __restrict__ ptr) {
    int c = blockIdx.x;
    int b = threadIdx.x;
    int deg = deg_arr[c];
    if (deg > ELLW) deg = ELLW;
    if (deg == 0) return;
    int base = ptr[c];
    float g = 1.0f / (1.0f + __builtin_amdgcn_exp2f(-gamma_logit[0] * LOG2E));
    float om = 1.0f - g;

    float tv[ELLW];

    // Process edges in batches of CHNK: loads unconditional (clamped) within a
    // batch so the compiler can pipeline them; one uniform branch per batch.
#define BATCH_BODY(J0)                                                         \
    {                                                                          \
        int4 r[CHNK]; float m0[CHNK], m1[CHNK], m2[CHNK], cv[CHNK], vo[CHNK];  \
        _Pragma("unroll")                                                      \
        for (int u = 0; u < CHNK; ++u) {                                       \
            int s = base + (J0) + u;                                           \
            s = (s < N_EDGE) ? s : (N_EDGE - 1);                               \
            r[u] = recs[s];                                                    \
        }                                                                      \
        _Pragma("unroll")                                                      \
        for (int u = 0; u < CHNK; ++u) {                                       \
            int s = base + (J0) + u;                                           \
            s = (s < N_EDGE) ? s : (N_EDGE - 1);                               \
            m0[u] = (float)c2v_prev[r[u].x * BATCH + b];                       \
            m1[u] = (float)c2v_prev[r[u].y * BATCH + b];                       \
            m2[u] = (float)c2v_prev[r[u].z * BATCH + b];                       \
            cv[u] = chn[(r[u].w >> 2) * BATCH + b];                            \
            vo[u] = (float)v2c[s * BATCH + b];                                 \
        }                                                                      \
        _Pragma("unroll")                                                      \
        for (int u = 0; u < CHNK; ++u) {                                       \
            int j = (J0) + u;                                                  \
            if (j < deg) {                                                     \
                int self = base + j;                                           \
                int v = r[u].w >> 2;                                           \
                float post = cv[u] + m0[u] + m1[u] + m2[u];                    \
                float cp = (r[u].x == self) ? m0[u]                            \
                           : ((r[u].y == self) ? m1[u] : m2[u]);               \
                float vn = g * (post - cp) + om * vo[u];                       \
                v2c[self * BATCH + b] = (_Float16)vn;                          \
                if (have_out && ((r[u].w & 3) == 0)) {                         \
                    __builtin_nontemporal_store(post,                          \
                        &out_prev[v * BATCH + b]);                             \
                }                                                              \
                float x = fminf(fmaxf(vn, -15.0f), 15.0f);                     \
                tv[j] = tanh_half(x);                                          \
            }                                                                  \
        }                                                                      \
    }

    BATCH_BODY(0)
    if (deg > CHNK) BATCH_BODY(CHNK)
    if (deg > 2 * CHNK) BATCH_BODY(2 * CHNK)
#undef BATCH_BODY

    // suffix products: ext[j] = prod_{k>j} tv[k]
    float ext[ELLW];
    float run = 1.0f;
#pragma unroll
    for (int j = ELLW - 1; j >= 0; --j) {
        if (j < deg) { ext[j] = run; run *= tv[j]; }
    }
    // prefix sweep + emit C2V (fp16, compact, coalesced)
    float pfx = 1.0f;
#pragma unroll
    for (int j = 0; j < ELLW; ++j) {
        if (j < deg) {
            float p = pfx * ext[j];
            pfx *= tv[j];
            float m = atanh2(p);
            c2v_curr[(base + j) * BATCH + b] = (_Float16)m;
        }
    }
}

// ---------------- final posterior slice (var-centric, coalesced) -----------

__global__ __launch_bounds__(256) void k_final(
        const float* __restrict__ chn, const _Float16* __restrict__ c2v,
        const int* __restrict__ slot_e, float* __restrict__ out_last) {
    int gid = blockIdx.x * 256 + threadIdx.x;   // 0 .. N_VAR*BATCH-1
    int v = gid >> 7;
    int b = gid & 127;
    int s0 = slot_e[3 * v + 0];
    int s1 = slot_e[3 * v + 1];
    int s2 = slot_e[3 * v + 2];
    float acc = chn[gid] + (float)c2v[s0 * BATCH + b] +
                (float)c2v[s1 * BATCH + b] + (float)c2v[s2 * BATCH + b];
    __builtin_nontemporal_store(acc, &out_last[gid]);
}

// ---------------- Launch ---------------------------------------------------

extern "C" void kernel_launch(void* const* d_in, const int* in_sizes, int n_in,
                              void* d_out, int out_size, void* d_ws, size_t ws_size,
                              hipStream_t stream) {
    const float* chn         = (const float*)d_in[0];
    const float* gamma_logit = (const float*)d_in[1];
    // d_in[2] = edge_var (deterministic: e/3) — not needed
    const int* edge_chk      = (const int*)d_in[3];
    float* out = (float*)d_out;

    const size_t MSG = (size_t)N_EDGE * BATCH;
    _Float16* c2vA   = (_Float16*)d_ws;                    // fp16 ping
    _Float16* c2vB   = c2vA + MSG;                         // fp16 pong
    _Float16* v2c    = c2vB + MSG;                         // fp16
    int4* recs       = (int4*)(v2c + MSG);                 // per-slot records
    int* slot_e      = (int*)(recs + N_EDGE);
    int* ell_e       = slot_e + N_EDGE;
    int* deg_arr     = ell_e + (size_t)N_CHK * ELLW;
    int* ptr         = deg_arr + N_CHK;                    // N_CHK+1 ints

    // zero ping + v2c in one shot (c2vA and v2c are not adjacent; two calls)
    (void)hipMemsetAsync(c2vA, 0, MSG * sizeof(_Float16), stream);
    (void)hipMemsetAsync(v2c, 0, MSG * sizeof(_Float16), stream);
    (void)hipMemsetAsync(slot_e, 0, (size_t)N_EDGE * sizeof(int), stream);
    (void)hipMemsetAsync(deg_arr, 0, N_CHK * sizeof(int), stream);

    k_ell_scatter<<<(N_EDGE + 255) / 256, 256, 0, stream>>>(edge_chk, deg_arr,
                                                            ell_e);
    k_scan<<<1, 1024, 0, stream>>>(deg_arr, ptr);
    k_slotmap<<<(N_CHK * ELLW + 255) / 256, 256, 0, stream>>>(ell_e, deg_arr,
                                                              ptr, slot_e);
    k_pack<<<(N_EDGE + 255) / 256, 256, 0, stream>>>(slot_e, recs);

    const size_t SLICE = (size_t)N_VAR * BATCH;
    _Float16* bufs[2] = {c2vA, c2vB};
    for (int t = 0; t < T_ITERS; ++t) {
        const _Float16* prev = bufs[t & 1];
        _Float16* curr = bufs[(t + 1) & 1];
        float* out_prev = (t == 0) ? out : out + (size_t)(t - 1) * SLICE;
        k_iter<<<N_CHK, 128, 0, stream>>>(chn, prev, curr, v2c, out_prev,
                                          (t > 0) ? 1 : 0, gamma_logit, recs,
                                          deg_arr, ptr);
    }
    // out[T-1] = chn + sum of final c2v (final buffer = bufs[T_ITERS & 1])
    k_final<<<(N_VAR * BATCH) / 256, 256, 0, stream>>>(
        chn, bufs[T_ITERS & 1], slot_e, out + (size_t)(T_ITERS - 1) * SLICE);
}

// Round 5
// 614.079 us; speedup vs baseline: 1.1485x; 1.0067x over previous
//
#include <hip/hip_runtime.h>
#include <math.h>

#define N_VAR 8192
#define N_CHK 4096
#define DV 3
#define N_EDGE (N_VAR * DV)
#define BATCH 128
#define HB (BATCH / 2)              /* 64 packed fp16-pair lanes per row */
#define T_ITERS 30
#define ELLW 24
#define CHNK 8

#define LOG2E 1.44269504088896340736f
#define LN2   0.69314718055994530942f

typedef _Float16 h2 __attribute__((ext_vector_type(2)));
typedef float f2 __attribute__((ext_vector_type(2)));

// tanh(x/2), sign preserved, |t| floored at 1e-7 (matches reference clamp);
// x pre-clipped to [-15,15]
__device__ __forceinline__ float tanh_half(float x) {
    float ex = __builtin_amdgcn_exp2f(x * LOG2E);              // e^x
    float t = 1.0f - 2.0f * __builtin_amdgcn_rcpf(ex + 1.0f);
    float s = (x < 0.0f) ? -1.0f : 1.0f;
    return s * fmaxf(fabsf(t), 1e-7f);
}

// 2*atanh(clip(p)) — reference's clip(-1+eps, 1-eps) then 2 atanh
__device__ __forceinline__ float atanh2(float p) {
    const float lim = 1.0f - 1e-7f;
    p = fminf(fmaxf(p, -lim), lim);
    return (__builtin_amdgcn_logf(1.0f + p) -
            __builtin_amdgcn_logf(1.0f - p)) * LN2;
}

// ---------------- graph build (once per launch) ----------------------------

__global__ void k_ell_scatter(const int* __restrict__ edge_chk,
                              int* __restrict__ deg_arr, int* __restrict__ ell_e) {
    int e = blockIdx.x * blockDim.x + threadIdx.x;
    if (e < N_EDGE) {
        int c = edge_chk[e];
        int pos = atomicAdd(&deg_arr[c], 1);
        if (pos < ELLW) ell_e[c * ELLW + pos] = e;   // store EDGE id
    }
}

// exclusive prefix over 4096 degs -> ptr (compact slot offsets)
__global__ __launch_bounds__(1024) void k_scan(const int* __restrict__ counts,
                                               int* __restrict__ ptr) {
    __shared__ int bufA[1024];
    __shared__ int bufB[1024];
    int t = threadIdx.x;
    int c0 = counts[4 * t + 0];
    int c1 = counts[4 * t + 1];
    int c2 = counts[4 * t + 2];
    int c3 = counts[4 * t + 3];
    int s = c0 + c1 + c2 + c3;
    bufA[t] = s;
    __syncthreads();
    int* src = bufA;
    int* dst = bufB;
    for (int off = 1; off < 1024; off *= 2) {
        int v = src[t];
        if (t >= off) v += src[t - off];
        dst[t] = v;
        __syncthreads();
        int* tmp = src; src = dst; dst = tmp;
    }
    int incl = src[t];
    int excl = incl - s;
    ptr[4 * t + 0] = excl;
    ptr[4 * t + 1] = excl + c0;
    ptr[4 * t + 2] = excl + c0 + c1;
    ptr[4 * t + 3] = excl + c0 + c1 + c2;
    if (t == 1023) ptr[N_CHK] = incl;
}

// slot_e[e] = compact slot of edge e
__global__ void k_slotmap(const int* __restrict__ ell_e,
                          const int* __restrict__ deg_arr,
                          const int* __restrict__ ptr,
                          int* __restrict__ slot_e) {
    int gid = blockIdx.x * 256 + threadIdx.x;
    if (gid < N_CHK * ELLW) {
        int c = gid / ELLW;
        int j = gid - c * ELLW;
        int d = deg_arr[c]; if (d > ELLW) d = ELLW;
        if (j < d) slot_e[ell_e[gid]] = ptr[c] + j;
    }
}

// slot4[v] = slots of v's 3 edges (one 16B load in the hot kernels)
__global__ void k_slot4(const int* __restrict__ slot_e, int4* __restrict__ slot4) {
    int v = blockIdx.x * 256 + threadIdx.x;
    if (v < N_VAR) {
        int4 s;
        s.x = slot_e[3 * v + 0];
        s.y = slot_e[3 * v + 1];
        s.z = slot_e[3 * v + 2];
        s.w = 0;
        slot4[v] = s;
    }
}

// ---------------- variable-centric half-iteration --------------------------
// lane handles 2 batch elements (fp16 pairs). Per variable:
//   post = chn + sum of its 3 C2V  (written to out[t-1] when have_out)
//   per edge i: v2c = g*(post - c_i) + (1-g)*v2c ; x = clip(v2c) -> slot i
// x (NOT tanh(x/2)) is stored fp16: tanh saturates to 1.0 in fp16 and
// destroys atanh precision; x<=15 carries full info at fp16.

__global__ __launch_bounds__(256) void k_var(
        const float* __restrict__ chn,
        const h2* __restrict__ c2v_prev,
        h2* __restrict__ v2c,
        h2* __restrict__ x_arr,
        float* __restrict__ out_prev,
        const int have_out,
        const float* __restrict__ gamma_logit,
        const int4* __restrict__ slot4) {
    int gid = blockIdx.x * 256 + threadIdx.x;    // 0 .. N_VAR*HB-1
    int v = gid >> 6;
    int bb = gid & 63;
    float g = 1.0f / (1.0f + __builtin_amdgcn_exp2f(-gamma_logit[0] * LOG2E));
    float om = 1.0f - g;

    int4 s4 = slot4[v];
    int sl[3] = {s4.x, s4.y, s4.z};
    h2 c0 = c2v_prev[s4.x * HB + bb];
    h2 c1 = c2v_prev[s4.y * HB + bb];
    h2 c2 = c2v_prev[s4.z * HB + bb];
    f2 ch = ((const f2*)chn)[v * HB + bb];

    float p0 = ch.x + (float)c0.x + (float)c1.x + (float)c2.x;
    float p1 = ch.y + (float)c0.y + (float)c1.y + (float)c2.y;
    if (have_out) {
        f2 o; o.x = p0; o.y = p1;
        __builtin_nontemporal_store(o, &((f2*)out_prev)[v * HB + bb]);
    }

    float cc0[3] = {(float)c0.x, (float)c1.x, (float)c2.x};
    float cc1[3] = {(float)c0.y, (float)c1.y, (float)c2.y};
#pragma unroll
    for (int i = 0; i < 3; ++i) {
        int vi = i * (N_VAR * HB) + v * HB + bb;
        h2 vo = v2c[vi];
        float vn0 = g * (p0 - cc0[i]) + om * (float)vo.x;
        float vn1 = g * (p1 - cc1[i]) + om * (float)vo.y;
        h2 w; w.x = (_Float16)vn0; w.y = (_Float16)vn1;
        v2c[vi] = w;
        float x0 = fminf(fmaxf(vn0, -15.0f), 15.0f);
        float x1 = fminf(fmaxf(vn1, -15.0f), 15.0f);
        h2 xw; xw.x = (_Float16)x0; xw.y = (_Float16)x1;
        x_arr[sl[i] * HB + bb] = xw;               // scattered, wave-coalesced
    }
}

// ---------------- check-centric half-iteration ------------------------------
// 4 checks per 256-thread block (one wave each). Fully coalesced reads of x,
// t = tanh(x/2) in f32, exact suffix/prefix extrinsic products (no division),
// C2V_curr = 2 atanh(clip(.)).

__global__ __launch_bounds__(256) void k_chk(
        const h2* __restrict__ x_arr,
        h2* __restrict__ c2v_curr,
        const int* __restrict__ deg_arr,
        const int* __restrict__ ptr) {
    int c = blockIdx.x * 4 + (threadIdx.x >> 6);
    int bb = threadIdx.x & 63;
    int deg = deg_arr[c];
    if (deg > ELLW) deg = ELLW;
    if (deg == 0) return;
    int base = ptr[c];

    f2 tv[ELLW];

#define LOAD_BATCH(J0)                                                         \
    {                                                                          \
        h2 raw[CHNK];                                                          \
        _Pragma("unroll")                                                      \
        for (int u = 0; u < CHNK; ++u) {                                       \
            int s = base + (J0) + u;                                           \
            s = (s < N_EDGE) ? s : (N_EDGE - 1);                               \
            raw[u] = x_arr[s * HB + bb];                                       \
        }                                                                      \
        _Pragma("unroll")                                                      \
        for (int u = 0; u < CHNK; ++u) {                                       \
            int j = (J0) + u;                                                  \
            if (j < deg) {                                                     \
                f2 tf;                                                         \
                tf.x = tanh_half((float)raw[u].x);                             \
                tf.y = tanh_half((float)raw[u].y);                             \
                tv[j] = tf;                                                    \
            }                                                                  \
        }                                                                      \
    }

    LOAD_BATCH(0)
    if (deg > CHNK) LOAD_BATCH(CHNK)
    if (deg > 2 * CHNK) LOAD_BATCH(2 * CHNK)
#undef LOAD_BATCH

    // suffix products: ext[j] = prod_{k>j} tv[k]
    f2 ext[ELLW];
    f2 run; run.x = 1.0f; run.y = 1.0f;
#pragma unroll
    for (int j = ELLW - 1; j >= 0; --j) {
        if (j < deg) {
            ext[j] = run;
            run.x *= tv[j].x; run.y *= tv[j].y;
        }
    }
    // prefix sweep + emit C2V (fp16, compact, coalesced)
    f2 pfx; pfx.x = 1.0f; pfx.y = 1.0f;
#pragma unroll
    for (int j = 0; j < ELLW; ++j) {
        if (j < deg) {
            float p0 = pfx.x * ext[j].x;
            float p1 = pfx.y * ext[j].y;
            pfx.x *= tv[j].x; pfx.y *= tv[j].y;
            h2 w;
            w.x = (_Float16)atanh2(p0);
            w.y = (_Float16)atanh2(p1);
            c2v_curr[(base + j) * HB + bb] = w;
        }
    }
}

// ---------------- final posterior slice (var-centric, coalesced) -----------

__global__ __launch_bounds__(256) void k_final(
        const float* __restrict__ chn, const h2* __restrict__ c2v,
        const int4* __restrict__ slot4, float* __restrict__ out_last) {
    int gid = blockIdx.x * 256 + threadIdx.x;    // 0 .. N_VAR*HB-1
    int v = gid >> 6;
    int bb = gid & 63;
    int4 s4 = slot4[v];
    h2 c0 = c2v[s4.x * HB + bb];
    h2 c1 = c2v[s4.y * HB + bb];
    h2 c2 = c2v[s4.z * HB + bb];
    f2 ch = ((const f2*)chn)[v * HB + bb];
    f2 o;
    o.x = ch.x + (float)c0.x + (float)c1.x + (float)c2.x;
    o.y = ch.y + (float)c0.y + (float)c1.y + (float)c2.y;
    __builtin_nontemporal_store(o, &((f2*)out_last)[v * HB + bb]);
}

// ---------------- Launch ---------------------------------------------------

extern "C" void kernel_launch(void* const* d_in, const int* in_sizes, int n_in,
                              void* d_out, int out_size, void* d_ws, size_t ws_size,
                              hipStream_t stream) {
    const float* chn         = (const float*)d_in[0];
    const float* gamma_logit = (const float*)d_in[1];
    // d_in[2] = edge_var (deterministic: e/3) — not needed
    const int* edge_chk      = (const int*)d_in[3];
    float* out = (float*)d_out;

    const size_t MSGH = (size_t)N_EDGE * HB;               // h2 elems per array
    h2* c2vA    = (h2*)d_ws;                               // ping
    h2* c2vB    = c2vA + MSGH;                             // pong
    h2* x_arr   = c2vB + MSGH;                             // clipped v2c values
    h2* v2c     = x_arr + MSGH;                            // 3 planes, var-order
    int4* slot4 = (int4*)(v2c + 3 * (size_t)N_VAR * HB);
    int* slot_e = (int*)(slot4 + N_VAR);
    int* ell_e  = slot_e + N_EDGE;
    int* deg_arr= ell_e + (size_t)N_CHK * ELLW;
    int* ptr    = deg_arr + N_CHK;                         // N_CHK+1 ints

    (void)hipMemsetAsync(c2vA, 0, MSGH * sizeof(h2), stream);
    (void)hipMemsetAsync(v2c, 0, 3 * (size_t)N_VAR * HB * sizeof(h2), stream);
    (void)hipMemsetAsync(slot_e, 0, (size_t)N_EDGE * sizeof(int), stream);
    (void)hipMemsetAsync(deg_arr, 0, N_CHK * sizeof(int), stream);

    k_ell_scatter<<<(N_EDGE + 255) / 256, 256, 0, stream>>>(edge_chk, deg_arr,
                                                            ell_e);
    k_scan<<<1, 1024, 0, stream>>>(deg_arr, ptr);
    k_slotmap<<<(N_CHK * ELLW + 255) / 256, 256, 0, stream>>>(ell_e, deg_arr,
                                                              ptr, slot_e);
    k_slot4<<<N_VAR / 256, 256, 0, stream>>>(slot_e, slot4);

    const size_t SLICE = (size_t)N_VAR * BATCH;
    h2* bufs[2] = {c2vA, c2vB};
    for (int t = 0; t < T_ITERS; ++t) {
        const h2* prev = bufs[t & 1];
        h2* curr = bufs[(t + 1) & 1];
        float* out_prev = (t == 0) ? out : out + (size_t)(t - 1) * SLICE;
        k_var<<<(N_VAR * HB) / 256, 256, 0, stream>>>(
            chn, prev, v2c, x_arr, out_prev, (t > 0) ? 1 : 0, gamma_logit, slot4);
        k_chk<<<N_CHK / 4, 256, 0, stream>>>(x_arr, curr, deg_arr, ptr);
    }
    // out[T-1] = chn + sum of final c2v (final buffer = bufs[T_ITERS & 1])
    k_final<<<(N_VAR * HB) / 256, 256, 0, stream>>>(
        chn, bufs[T_ITERS & 1], slot4, out + (size_t)(T_ITERS - 1) * SLICE);
}